// Round 1
// baseline (396.950 us; speedup 1.0000x reference)
//
#include <hip/hip_runtime.h>
#include <stdint.h>

// ---------------------------------------------------------------------------
// TripletRankingLoss: replicate JAX reference exactly.
//   - idx_p/idx_n come from gumbel-argmax with threefry2x32 RNG, key 42.
//   - gumbel = -log(-log(u)) is strictly monotonic in the raw 23-bit draw
//     (bits >> 9), so we argmax the INTEGER draw (no logs, no float error),
//     with first-index tie-breaking to match jnp.argmax.
//   - JAX_PARTITIONABLE=1 assumes jax_threefry_partitionable=True (JAX
//     default since 0.4.30). Flip to 0 for the legacy counting scheme.
// ---------------------------------------------------------------------------

#define JAX_PARTITIONABLE 1

#define B_ROWS 8192
#define DIMS   512

__device__ __forceinline__ void tf_block(uint32_t k0, uint32_t k1,
                                         uint32_t x0, uint32_t x1,
                                         uint32_t& o0, uint32_t& o1) {
  const uint32_t ks0 = k0, ks1 = k1, ks2 = k0 ^ k1 ^ 0x1BD11BDAu;
  x0 += ks0; x1 += ks1;
#define TFR(r) { x0 += x1; x1 = (x1 << (r)) | (x1 >> (32 - (r))); x1 ^= x0; }
  TFR(13) TFR(15) TFR(26) TFR(6)
  x0 += ks1; x1 += ks2 + 1u;
  TFR(17) TFR(29) TFR(16) TFR(24)
  x0 += ks2; x1 += ks0 + 2u;
  TFR(13) TFR(15) TFR(26) TFR(6)
  x0 += ks0; x1 += ks1 + 3u;
  TFR(17) TFR(29) TFR(16) TFR(24)
  x0 += ks1; x1 += ks2 + 4u;
  TFR(13) TFR(15) TFR(26) TFR(6)
  x0 += ks2; x1 += ks0 + 5u;
#undef TFR
  o0 = x0; o1 = x1;
}

// jax.random.key(42) -> key data (0, 42); split -> kp (elem 0), kn (elem 1)
__device__ __forceinline__ void derive_keys(uint32_t& kp0, uint32_t& kp1,
                                            uint32_t& kn0, uint32_t& kn1) {
#if JAX_PARTITIONABLE
  // fold-like split: new_key[i] = full block output for counts (0, i)
  tf_block(0u, 42u, 0u, 0u, kp0, kp1);
  tf_block(0u, 42u, 0u, 1u, kn0, kn1);
#else
  // original split: counts [0,1,2,3] -> halves x0=[0,1], x1=[2,3]
  uint32_t a0, b0, a1, b1;
  tf_block(0u, 42u, 0u, 2u, a0, b0);
  tf_block(0u, 42u, 1u, 3u, a1, b1);
  kp0 = a0; kp1 = a1; kn0 = b0; kn1 = b1;
#endif
}

// 32-bit draw for flat index m of a (8192, 8192) array
__device__ __forceinline__ uint32_t rand_word(uint32_t k0, uint32_t k1, uint32_t m) {
#if JAX_PARTITIONABLE
  uint32_t o0, o1;
  tf_block(k0, k1, 0u, m, o0, o1);  // counts = (hi32(m)=0, lo32(m)=m)
  return o0 ^ o1;
#else
  const uint32_t HALF = 1u << 25;   // n = 2^26 elements, even
  uint32_t o0, o1;
  if (m < HALF) { tf_block(k0, k1, m, m + HALF, o0, o1); return o0; }
  else          { tf_block(k0, k1, m - HALF, m, o0, o1); return o1; }
#endif
}

// --------------------------- kernel 1: row norms ---------------------------
__global__ __launch_bounds__(256) void norms_kernel(const float* __restrict__ pred,
                                                    float* __restrict__ norms) {
  const int wave = threadIdx.x >> 6, lane = threadIdx.x & 63;
  const int r = blockIdx.x * 4 + wave;
  const float4* A = (const float4*)(pred + (size_t)r * DIMS);
  float s = 0.f;
#pragma unroll
  for (int t = 0; t < 2; ++t) {
    const float4 a = A[lane + 64 * t];
    s += a.x * a.x + a.y * a.y + a.z * a.z + a.w * a.w;
  }
  for (int o = 32; o > 0; o >>= 1) s += __shfl_down(s, o, 64);
  if (lane == 0) norms[r] = sqrtf(s);
}

// ----------------- kernel 2: masked gumbel argmax (pos & neg) --------------
__global__ __launch_bounds__(256) void argmax_kernel(const int* __restrict__ labels,
                                                     int* __restrict__ idxp,
                                                     int* __restrict__ idxn) {
  __shared__ unsigned long long sh[8];
  const int i = blockIdx.x;
  const int li = labels[i];
  uint32_t kp0, kp1, kn0, kn1;
  derive_keys(kp0, kp1, kn0, kn1);
  const uint32_t base = (uint32_t)i << 13;  // i * 8192

  int bvp = -1, bip = 0;   // best positive (val, idx); val=-1 => none seen
  int bvn = -1, bin_ = 0;  // best negative
  for (int j = threadIdx.x; j < B_ROWS; j += 256) {
    const int lj = labels[j];
    const uint32_t m = base + (uint32_t)j;
    const uint32_t wp = rand_word(kp0, kp1, m);
    const uint32_t wn = rand_word(kn0, kn1, m);
    const int vp = (int)(wp >> 9);  // 23-bit draw; monotonic in gumbel value
    const int vn = (int)(wn >> 9);
    if (lj == li) { if (vp > bvp) { bvp = vp; bip = j; } }   // ascending j:
    else          { if (vn > bvn) { bvn = vn; bin_ = j; } }  // strict > = first-max
  }
  // pack: (val+1)<<13 | (8191-idx)  -> max = max val, tie -> min idx
  unsigned long long pp = (((unsigned long long)(bvp + 1)) << 13) | (unsigned)(8191 - bip);
  unsigned long long pn = (((unsigned long long)(bvn + 1)) << 13) | (unsigned)(8191 - bin_);
  for (int o = 32; o > 0; o >>= 1) {
    const unsigned long long t1 = __shfl_down(pp, o, 64); if (t1 > pp) pp = t1;
    const unsigned long long t2 = __shfl_down(pn, o, 64); if (t2 > pn) pn = t2;
  }
  const int wave = threadIdx.x >> 6, lane = threadIdx.x & 63;
  if (lane == 0) { sh[wave] = pp; sh[4 + wave] = pn; }
  __syncthreads();
  if (threadIdx.x == 0) {
    unsigned long long a = sh[0], b = sh[4];
    for (int w = 1; w < 4; ++w) {
      if (sh[w] > a) a = sh[w];
      if (sh[4 + w] > b) b = sh[4 + w];
    }
    idxp[i] = 8191 - (int)(a & 8191ull);
    idxn[i] = 8191 - (int)(b & 8191ull);
  }
}

// --------------- kernel 3: per-row cosine margin, relu -> cosv -------------
__global__ __launch_bounds__(256) void cos_kernel(const float* __restrict__ pred,
                                                  const float* __restrict__ norms,
                                                  const int* __restrict__ idxp,
                                                  const int* __restrict__ idxn,
                                                  float* __restrict__ cosv) {
  const int wave = threadIdx.x >> 6, lane = threadIdx.x & 63;
  const int r = blockIdx.x * 4 + wave;
  const int ip = idxp[r], inn = idxn[r];
  const float4* A = (const float4*)(pred + (size_t)r * DIMS);
  const float4* P = (const float4*)(pred + (size_t)ip * DIMS);
  const float4* Nn = (const float4*)(pred + (size_t)inn * DIMS);
  float dp = 0.f, dn = 0.f;
#pragma unroll
  for (int t = 0; t < 2; ++t) {
    const float4 a = A[lane + 64 * t];
    const float4 p = P[lane + 64 * t];
    const float4 n = Nn[lane + 64 * t];
    dp += a.x * p.x + a.y * p.y + a.z * p.z + a.w * p.w;
    dn += a.x * n.x + a.y * n.y + a.z * n.z + a.w * n.w;
  }
  for (int o = 32; o > 0; o >>= 1) {
    dp += __shfl_down(dp, o, 64);
    dn += __shfl_down(dn, o, 64);
  }
  if (lane == 0) {
    const float na = fmaxf(norms[r], 1e-6f);
    const float np = fmaxf(norms[ip], 1e-6f);
    const float nn = fmaxf(norms[inn], 1e-6f);
    const float c = dp / (na * np) - dn / (na * nn) + 0.1f;
    cosv[r] = fmaxf(c, 0.f);
  }
}

// --------------------- kernel 4: mean (double accumulate) ------------------
__global__ __launch_bounds__(256) void reduce_kernel(const float* __restrict__ cosv,
                                                     float* __restrict__ out) {
  __shared__ double sh[4];
  double s = 0.0;
  for (int j = threadIdx.x; j < B_ROWS; j += 256) s += (double)cosv[j];
  for (int o = 32; o > 0; o >>= 1) s += __shfl_down(s, o, 64);
  const int wave = threadIdx.x >> 6, lane = threadIdx.x & 63;
  if (lane == 0) sh[wave] = s;
  __syncthreads();
  if (threadIdx.x == 0) {
    const double t = sh[0] + sh[1] + sh[2] + sh[3];
    out[0] = (float)(t / (double)B_ROWS);
  }
}

extern "C" void kernel_launch(void* const* d_in, const int* in_sizes, int n_in,
                              void* d_out, int out_size, void* d_ws, size_t ws_size,
                              hipStream_t stream) {
  const float* pred  = (const float*)d_in[0];
  const int* labels  = (const int*)d_in[1];
  float* out = (float*)d_out;

  char* ws = (char*)d_ws;
  float* norms = (float*)(ws + 0);
  int*   idxp  = (int*)(ws + 32 * 1024);
  int*   idxn  = (int*)(ws + 64 * 1024);
  float* cosv  = (float*)(ws + 96 * 1024);

  norms_kernel<<<B_ROWS / 4, 256, 0, stream>>>(pred, norms);
  argmax_kernel<<<B_ROWS, 256, 0, stream>>>(labels, idxp, idxn);
  cos_kernel<<<B_ROWS / 4, 256, 0, stream>>>(pred, norms, idxp, idxn, cosv);
  reduce_kernel<<<1, 256, 0, stream>>>(cosv, out);
}

// Round 3
// 310.543 us; speedup vs baseline: 1.2782x; 1.2782x over previous
//
#include <hip/hip_runtime.h>
#include <stdint.h>

// ---------------------------------------------------------------------------
// TripletRankingLoss — bit-exact JAX replication (verified absmax 0.0 in R1
// with jax_threefry_partitionable=True scheme).
//
// R2 changes (argmax kernel only, 87% of runtime, VALUBusy 96%):
//   1. ONE threefry block per (i,j) instead of two: at each position exactly
//      one of {g_pos, g_neg} is consumed (pos iff labels match), so select
//      the key schedule per-lane (3 cndmask) and run a single block.
//   2. rotl via __builtin_amdgcn_alignbit -> guaranteed v_alignbit_b32
//      (3 VALU ops/round instead of shl+shr+or's 5).
//   Draw words are bit-identical to R1; argmax/tie-break logic unchanged.
// ---------------------------------------------------------------------------

#define B_ROWS 8192
#define DIMS   512

__device__ __forceinline__ uint32_t rotl(uint32_t x, uint32_t r) {
  // alignbit(a,b,s) = ((uint64(a)<<32 | b) >> s) & 0xffffffff; a==b => rotr(x,s)
  return __builtin_amdgcn_alignbit(x, x, 32u - r);
}

// Full threefry2x32 block (for key derivation; returns both words)
__device__ __forceinline__ void tf_block(uint32_t k0, uint32_t k1,
                                         uint32_t x0, uint32_t x1,
                                         uint32_t& o0, uint32_t& o1) {
  const uint32_t ks2 = k0 ^ k1 ^ 0x1BD11BDAu;
  x0 += k0; x1 += k1;
#define TFR(r) { x0 += x1; x1 = rotl(x1, r); x1 ^= x0; }
  TFR(13) TFR(15) TFR(26) TFR(6)
  x0 += k1;  x1 += ks2 + 1u;
  TFR(17) TFR(29) TFR(16) TFR(24)
  x0 += ks2; x1 += k0 + 2u;
  TFR(13) TFR(15) TFR(26) TFR(6)
  x0 += k0;  x1 += k1 + 3u;
  TFR(17) TFR(29) TFR(16) TFR(24)
  x0 += k1;  x1 += ks2 + 4u;
  TFR(13) TFR(15) TFR(26) TFR(6)
  x0 += ks2; x1 += k0 + 5u;
#undef TFR
  o0 = x0; o1 = x1;
}

// Single-word draw for counts (0, m): returns o0 ^ o1 (partitionable scheme).
// ks2 precomputed by caller (per-lane selected).
__device__ __forceinline__ uint32_t tf_draw(uint32_t k0, uint32_t k1,
                                            uint32_t ks2, uint32_t m) {
  uint32_t x0 = k0;        // 0 + ks0
  uint32_t x1 = m + k1;    // m + ks1
#define TFR(r) { x0 += x1; x1 = rotl(x1, r); x1 ^= x0; }
  TFR(13) TFR(15) TFR(26) TFR(6)
  x0 += k1;  x1 += ks2 + 1u;
  TFR(17) TFR(29) TFR(16) TFR(24)
  x0 += ks2; x1 += k0 + 2u;
  TFR(13) TFR(15) TFR(26) TFR(6)
  x0 += k0;  x1 += k1 + 3u;
  TFR(17) TFR(29) TFR(16) TFR(24)
  x0 += k1;  x1 += ks2 + 4u;
  TFR(13) TFR(15) TFR(26) TFR(6)
  x0 += ks2; x1 += k0 + 5u;
#undef TFR
  return x0 ^ x1;
}

// jax.random.key(42) -> (0, 42); partitionable split -> block at counts (0, i)
__device__ __forceinline__ void derive_keys(uint32_t& kp0, uint32_t& kp1,
                                            uint32_t& kn0, uint32_t& kn1) {
  tf_block(0u, 42u, 0u, 0u, kp0, kp1);
  tf_block(0u, 42u, 0u, 1u, kn0, kn1);
}

// --------------------------- kernel 1: row norms ---------------------------
__global__ __launch_bounds__(256) void norms_kernel(const float* __restrict__ pred,
                                                    float* __restrict__ norms) {
  const int wave = threadIdx.x >> 6, lane = threadIdx.x & 63;
  const int r = blockIdx.x * 4 + wave;
  const float4* A = (const float4*)(pred + (size_t)r * DIMS);
  float s = 0.f;
#pragma unroll
  for (int t = 0; t < 2; ++t) {
    const float4 a = A[lane + 64 * t];
    s += a.x * a.x + a.y * a.y + a.z * a.z + a.w * a.w;
  }
  for (int o = 32; o > 0; o >>= 1) s += __shfl_down(s, o, 64);
  if (lane == 0) norms[r] = sqrtf(s);
}

// ----------------- kernel 2: masked gumbel argmax (pos & neg) --------------
__global__ __launch_bounds__(256) void argmax_kernel(const int* __restrict__ labels,
                                                     int* __restrict__ idxp,
                                                     int* __restrict__ idxn) {
  __shared__ unsigned long long sh[8];
  const int i = blockIdx.x;
  const int li = labels[i];
  uint32_t kp0, kp1, kn0, kn1;
  derive_keys(kp0, kp1, kn0, kn1);
  // uniform across the grid -> hoist to SGPRs so per-lane selects read SGPR
  kp0 = (uint32_t)__builtin_amdgcn_readfirstlane((int)kp0);
  kp1 = (uint32_t)__builtin_amdgcn_readfirstlane((int)kp1);
  kn0 = (uint32_t)__builtin_amdgcn_readfirstlane((int)kn0);
  kn1 = (uint32_t)__builtin_amdgcn_readfirstlane((int)kn1);
  const uint32_t ksp2 = kp0 ^ kp1 ^ 0x1BD11BDAu;
  const uint32_t ksn2 = kn0 ^ kn1 ^ 0x1BD11BDAu;
  const uint32_t base = (uint32_t)i << 13;  // i * 8192

  int bvp = -1, bip = 0;   // best positive (23-bit val, idx)
  int bvn = -1, bin_ = 0;  // best negative
#pragma unroll 4
  for (int j = threadIdx.x; j < B_ROWS; j += 256) {
    const bool isp = (labels[j] == li);
    // exactly one of the two draws is consumed at this position -> one block
    const uint32_t k0  = isp ? kp0 : kn0;
    const uint32_t k1  = isp ? kp1 : kn1;
    const uint32_t ks2 = isp ? ksp2 : ksn2;
    const uint32_t w = tf_draw(k0, k1, ks2, base + (uint32_t)j);
    const int v = (int)(w >> 9);  // 23-bit draw; gumbel is monotonic in this
    if (isp) { if (v > bvp) { bvp = v; bip = j; } }   // strict > over ascending
    else     { if (v > bvn) { bvn = v; bin_ = j; } }  // j = first-index-wins
  }
  // pack: (val+1)<<13 | (8191-idx)  -> max = max val, tie -> min idx
  unsigned long long pp = (((unsigned long long)(bvp + 1)) << 13) | (unsigned)(8191 - bip);
  unsigned long long pn = (((unsigned long long)(bvn + 1)) << 13) | (unsigned)(8191 - bin_);
  for (int o = 32; o > 0; o >>= 1) {
    const unsigned long long t1 = __shfl_down(pp, o, 64); if (t1 > pp) pp = t1;
    const unsigned long long t2 = __shfl_down(pn, o, 64); if (t2 > pn) pn = t2;
  }
  const int wave = threadIdx.x >> 6, lane = threadIdx.x & 63;
  if (lane == 0) { sh[wave] = pp; sh[4 + wave] = pn; }
  __syncthreads();
  if (threadIdx.x == 0) {
    unsigned long long a = sh[0], b = sh[4];
    for (int w = 1; w < 4; ++w) {
      if (sh[w] > a) a = sh[w];
      if (sh[4 + w] > b) b = sh[4 + w];
    }
    idxp[i] = 8191 - (int)(a & 8191ull);
    idxn[i] = 8191 - (int)(b & 8191ull);
  }
}

// --------------- kernel 3: per-row cosine margin, relu -> cosv -------------
__global__ __launch_bounds__(256) void cos_kernel(const float* __restrict__ pred,
                                                  const float* __restrict__ norms,
                                                  const int* __restrict__ idxp,
                                                  const int* __restrict__ idxn,
                                                  float* __restrict__ cosv) {
  const int wave = threadIdx.x >> 6, lane = threadIdx.x & 63;
  const int r = blockIdx.x * 4 + wave;
  const int ip = idxp[r], inn = idxn[r];
  const float4* A = (const float4*)(pred + (size_t)r * DIMS);
  const float4* P = (const float4*)(pred + (size_t)ip * DIMS);
  const float4* Nn = (const float4*)(pred + (size_t)inn * DIMS);
  float dp = 0.f, dn = 0.f;
#pragma unroll
  for (int t = 0; t < 2; ++t) {
    const float4 a = A[lane + 64 * t];
    const float4 p = P[lane + 64 * t];
    const float4 n = Nn[lane + 64 * t];
    dp += a.x * p.x + a.y * p.y + a.z * p.z + a.w * p.w;
    dn += a.x * n.x + a.y * n.y + a.z * n.z + a.w * n.w;
  }
  for (int o = 32; o > 0; o >>= 1) {
    dp += __shfl_down(dp, o, 64);
    dn += __shfl_down(dn, o, 64);
  }
  if (lane == 0) {
    const float na = fmaxf(norms[r], 1e-6f);
    const float np = fmaxf(norms[ip], 1e-6f);
    const float nn = fmaxf(norms[inn], 1e-6f);
    const float c = dp / (na * np) - dn / (na * nn) + 0.1f;
    cosv[r] = fmaxf(c, 0.f);
  }
}

// --------------------- kernel 4: mean (double accumulate) ------------------
__global__ __launch_bounds__(256) void reduce_kernel(const float* __restrict__ cosv,
                                                     float* __restrict__ out) {
  __shared__ double sh[4];
  double s = 0.0;
  for (int j = threadIdx.x; j < B_ROWS; j += 256) s += (double)cosv[j];
  for (int o = 32; o > 0; o >>= 1) s += __shfl_down(s, o, 64);
  const int wave = threadIdx.x >> 6, lane = threadIdx.x & 63;
  if (lane == 0) sh[wave] = s;
  __syncthreads();
  if (threadIdx.x == 0) {
    const double t = sh[0] + sh[1] + sh[2] + sh[3];
    out[0] = (float)(t / (double)B_ROWS);
  }
}

extern "C" void kernel_launch(void* const* d_in, const int* in_sizes, int n_in,
                              void* d_out, int out_size, void* d_ws, size_t ws_size,
                              hipStream_t stream) {
  const float* pred  = (const float*)d_in[0];
  const int* labels  = (const int*)d_in[1];
  float* out = (float*)d_out;

  char* ws = (char*)d_ws;
  float* norms = (float*)(ws + 0);
  int*   idxp  = (int*)(ws + 32 * 1024);
  int*   idxn  = (int*)(ws + 64 * 1024);
  float* cosv  = (float*)(ws + 96 * 1024);

  norms_kernel<<<B_ROWS / 4, 256, 0, stream>>>(pred, norms);
  argmax_kernel<<<B_ROWS, 256, 0, stream>>>(labels, idxp, idxn);
  cos_kernel<<<B_ROWS / 4, 256, 0, stream>>>(pred, norms, idxp, idxn, cosv);
  reduce_kernel<<<1, 256, 0, stream>>>(cosv, out);
}

// Round 4
// 229.041 us; speedup vs baseline: 1.7331x; 1.3558x over previous
//
#include <hip/hip_runtime.h>
#include <stdint.h>

// ---------------------------------------------------------------------------
// TripletRankingLoss — bit-exact JAX replication (absmax 0.0 verified R1/R3,
// jax_threefry_partitionable=True scheme).
//
// R4: label-grouped permutation removes ALL per-iteration key selection and
// label compares from the hot argmax loop (was ~280 issued ops/position vs
// ~80 counted for the threefry core + update):
//   - sort_kernel: stable counting sort of [0,8192) by label (14 groups),
//     one block, LDS 16KB. Gives perm[] + group starts.
//   - argmax_kernel: one WAVE per row. Phase 1 iterates the row's own group
//     with compile-time-constant key KP (constexpr-derived -> literals);
//     phase 2 iterates the complement with KN. No labels load, no cndmask
//     key select, no divergent dual-tracker update.
//   - exact (value, index) pair-compare for first-index tie-break (cross-
//     group visit order is not ascending; ~7 rows/call have tied maxima).
// Draw words bit-identical to R1/R3.
// ---------------------------------------------------------------------------

#define B_ROWS 8192
#define DIMS   512
#define NLAB   16   // labels are 0..13; padded to 16

__device__ __forceinline__ uint32_t rotl(uint32_t x, uint32_t r) {
  return __builtin_amdgcn_alignbit(x, x, 32u - r);  // rotr(x, 32-r) == rotl(x, r)
}

// ---- compile-time threefry block for key derivation (pure literals) -------
struct KeyPair { uint32_t a, b; };
constexpr KeyPair tf_c(uint32_t k0, uint32_t k1, uint32_t x0, uint32_t x1) {
  const uint32_t ks2 = k0 ^ k1 ^ 0x1BD11BDAu;
  x0 += k0; x1 += k1;
#define TFRC(r) { x0 += x1; x1 = (uint32_t)((x1 << (r)) | (x1 >> (32 - (r)))); x1 ^= x0; }
  TFRC(13) TFRC(15) TFRC(26) TFRC(6)
  x0 += k1;  x1 += ks2 + 1u;
  TFRC(17) TFRC(29) TFRC(16) TFRC(24)
  x0 += ks2; x1 += k0 + 2u;
  TFRC(13) TFRC(15) TFRC(26) TFRC(6)
  x0 += k0;  x1 += k1 + 3u;
  TFRC(17) TFRC(29) TFRC(16) TFRC(24)
  x0 += k1;  x1 += ks2 + 4u;
  TFRC(13) TFRC(15) TFRC(26) TFRC(6)
  x0 += ks2; x1 += k0 + 5u;
#undef TFRC
  return {x0, x1};
}
// jax.random.key(42) -> (0,42); partitionable split -> block at counts (0, i)
constexpr KeyPair KP = tf_c(0u, 42u, 0u, 0u);  // kp = keys for g_pos
constexpr KeyPair KN = tf_c(0u, 42u, 0u, 1u);  // kn = keys for g_neg

// ---- runtime draw: keys are template literals; x1_init = m + K1 -----------
template <uint32_t K0, uint32_t K1>
__device__ __forceinline__ uint32_t tf_draw(uint32_t x1) {
  constexpr uint32_t KS2 = K0 ^ K1 ^ 0x1BD11BDAu;
  uint32_t x0 = K0;  // first TFR's add folds this init: x0 = K0 + x1
#define TFR(r) { x0 += x1; x1 = rotl(x1, r); x1 ^= x0; }
  TFR(13) TFR(15) TFR(26) TFR(6)
  x0 += K1;  x1 += KS2 + 1u;
  TFR(17) TFR(29) TFR(16) TFR(24)
  x0 += KS2; x1 += K0 + 2u;
  TFR(13) TFR(15) TFR(26) TFR(6)
  x0 += K0;  x1 += K1 + 3u;
  TFR(17) TFR(29) TFR(16) TFR(24)
  x0 += K1;  x1 += KS2 + 4u;
  TFR(13) TFR(15) TFR(26) TFR(6)
  x0 += KS2; x1 += K0 + 5u;
#undef TFR
  return x0 ^ x1;
}

// ---------------- kernel 0: stable counting sort by label ------------------
__global__ __launch_bounds__(256) void sort_kernel(const int* __restrict__ labels,
                                                   int* __restrict__ perm,
                                                   int* __restrict__ gstart) {
  __shared__ int cnt[NLAB][256];
  __shared__ int gs[NLAB + 1];
  const int t = threadIdx.x;
  for (int l = 0; l < NLAB; ++l) cnt[l][t] = 0;
  __syncthreads();
  const int base = t * 32;  // chunked: global ascending order = (t, local) order
  for (int e = base; e < base + 32; ++e) cnt[labels[e]][t]++;
  __syncthreads();
  if (t < NLAB) {  // per-label exclusive scan over threads
    int run = 0;
    for (int k = 0; k < 256; ++k) { const int c = cnt[t][k]; cnt[t][k] = run; run += c; }
    gs[t + 1] = run;  // total count of label t
  }
  __syncthreads();
  if (t == 0) {
    gs[0] = 0;
    for (int l = 1; l <= NLAB; ++l) gs[l] += gs[l - 1];
  }
  __syncthreads();
  for (int e = base; e < base + 32; ++e) {  // stable scatter
    const int l = labels[e];
    perm[gs[l] + cnt[l][t]++] = e;
  }
  if (t <= NLAB) gstart[t] = gs[t];
}

// --------------------------- kernel 1: row norms ---------------------------
__global__ __launch_bounds__(256) void norms_kernel(const float* __restrict__ pred,
                                                    float* __restrict__ norms) {
  const int wave = threadIdx.x >> 6, lane = threadIdx.x & 63;
  const int r = blockIdx.x * 4 + wave;
  const float4* A = (const float4*)(pred + (size_t)r * DIMS);
  float s = 0.f;
#pragma unroll
  for (int t = 0; t < 2; ++t) {
    const float4 a = A[lane + 64 * t];
    s += a.x * a.x + a.y * a.y + a.z * a.z + a.w * a.w;
  }
  for (int o = 32; o > 0; o >>= 1) s += __shfl_down(s, o, 64);
  if (lane == 0) norms[r] = sqrtf(s);
}

// ------------- kernel 2: gumbel argmax, one wave per row -------------------
__global__ __launch_bounds__(256) void argmax_kernel(const int* __restrict__ labels,
                                                     const int* __restrict__ perm,
                                                     const int* __restrict__ gstart,
                                                     int* __restrict__ idxp,
                                                     int* __restrict__ idxn) {
  const int lane = threadIdx.x & 63;
  const int r = blockIdx.x * 4 + (threadIdx.x >> 6);
  const int li = __builtin_amdgcn_readfirstlane(labels[r]);
  const int g0 = __builtin_amdgcn_readfirstlane(gstart[li]);
  const int g1 = __builtin_amdgcn_readfirstlane(gstart[li + 1]);
  const uint32_t base = (uint32_t)r << 13;  // r * 8192

  // ---- positive phase: own group, key KP ----
  int bv = -1, bi = 0;
  const uint32_t sbp = base + KP.b;
  for (int t = g0 + lane; t < g1; t += 64) {
    const int j = perm[t];
    const uint32_t w = tf_draw<KP.a, KP.b>(sbp + (uint32_t)j);
    const int v = (int)(w >> 9);  // 23-bit draw; gumbel monotonic in this
    const bool better = (v > bv) || ((v == bv) && (j < bi));
    bv = better ? v : bv;
    bi = better ? j : bi;
  }
  unsigned long long pp =
      (((unsigned long long)(bv + 1)) << 13) | (unsigned)(8191 - bi);

  // ---- negative phase: complement, key KN ----
  bv = -1; bi = 0;
  const int glen = g1 - g0;
  const int nneg = B_ROWS - glen;
  const uint32_t sbn = base + KN.b;
#pragma unroll 2
  for (int t = lane; t < nneg; t += 64) {
    const int tj = (t < g0) ? t : (t + glen);  // skip own group
    const int j = perm[tj];
    const uint32_t w = tf_draw<KN.a, KN.b>(sbn + (uint32_t)j);
    const int v = (int)(w >> 9);
    const bool better = (v > bv) || ((v == bv) && (j < bi));
    bv = better ? v : bv;
    bi = better ? j : bi;
  }
  unsigned long long pn =
      (((unsigned long long)(bv + 1)) << 13) | (unsigned)(8191 - bi);

  // ---- wave reduce: max value, tie -> min index (packed) ----
  for (int o = 32; o > 0; o >>= 1) {
    const unsigned long long t1 = __shfl_down(pp, o, 64); if (t1 > pp) pp = t1;
    const unsigned long long t2 = __shfl_down(pn, o, 64); if (t2 > pn) pn = t2;
  }
  if (lane == 0) {
    idxp[r] = 8191 - (int)(pp & 8191ull);
    idxn[r] = 8191 - (int)(pn & 8191ull);
  }
}

// --------------- kernel 3: per-row cosine margin, relu -> cosv -------------
__global__ __launch_bounds__(256) void cos_kernel(const float* __restrict__ pred,
                                                  const float* __restrict__ norms,
                                                  const int* __restrict__ idxp,
                                                  const int* __restrict__ idxn,
                                                  float* __restrict__ cosv) {
  const int wave = threadIdx.x >> 6, lane = threadIdx.x & 63;
  const int r = blockIdx.x * 4 + wave;
  const int ip = idxp[r], inn = idxn[r];
  const float4* A = (const float4*)(pred + (size_t)r * DIMS);
  const float4* P = (const float4*)(pred + (size_t)ip * DIMS);
  const float4* Nn = (const float4*)(pred + (size_t)inn * DIMS);
  float dp = 0.f, dn = 0.f;
#pragma unroll
  for (int t = 0; t < 2; ++t) {
    const float4 a = A[lane + 64 * t];
    const float4 p = P[lane + 64 * t];
    const float4 n = Nn[lane + 64 * t];
    dp += a.x * p.x + a.y * p.y + a.z * p.z + a.w * p.w;
    dn += a.x * n.x + a.y * n.y + a.z * n.z + a.w * n.w;
  }
  for (int o = 32; o > 0; o >>= 1) {
    dp += __shfl_down(dp, o, 64);
    dn += __shfl_down(dn, o, 64);
  }
  if (lane == 0) {
    const float na = fmaxf(norms[r], 1e-6f);
    const float np = fmaxf(norms[ip], 1e-6f);
    const float nn = fmaxf(norms[inn], 1e-6f);
    const float c = dp / (na * np) - dn / (na * nn) + 0.1f;
    cosv[r] = fmaxf(c, 0.f);
  }
}

// --------------------- kernel 4: mean (double accumulate) ------------------
__global__ __launch_bounds__(256) void reduce_kernel(const float* __restrict__ cosv,
                                                     float* __restrict__ out) {
  __shared__ double sh[4];
  double s = 0.0;
  for (int j = threadIdx.x; j < B_ROWS; j += 256) s += (double)cosv[j];
  for (int o = 32; o > 0; o >>= 1) s += __shfl_down(s, o, 64);
  const int wave = threadIdx.x >> 6, lane = threadIdx.x & 63;
  if (lane == 0) sh[wave] = s;
  __syncthreads();
  if (threadIdx.x == 0) {
    const double t = sh[0] + sh[1] + sh[2] + sh[3];
    out[0] = (float)(t / (double)B_ROWS);
  }
}

extern "C" void kernel_launch(void* const* d_in, const int* in_sizes, int n_in,
                              void* d_out, int out_size, void* d_ws, size_t ws_size,
                              hipStream_t stream) {
  const float* pred  = (const float*)d_in[0];
  const int* labels  = (const int*)d_in[1];
  float* out = (float*)d_out;

  char* ws = (char*)d_ws;
  float* norms  = (float*)(ws + 0);
  int*   idxp   = (int*)(ws + 32 * 1024);
  int*   idxn   = (int*)(ws + 64 * 1024);
  float* cosv   = (float*)(ws + 96 * 1024);
  int*   perm   = (int*)(ws + 128 * 1024);
  int*   gstart = (int*)(ws + 160 * 1024);

  sort_kernel<<<1, 256, 0, stream>>>(labels, perm, gstart);
  norms_kernel<<<B_ROWS / 4, 256, 0, stream>>>(pred, norms);
  argmax_kernel<<<B_ROWS / 4, 256, 0, stream>>>(labels, perm, gstart, idxp, idxn);
  cos_kernel<<<B_ROWS / 4, 256, 0, stream>>>(pred, norms, idxp, idxn, cosv);
  reduce_kernel<<<1, 256, 0, stream>>>(cosv, out);
}